// Round 4
// baseline (3614.080 us; speedup 1.0000x reference)
//
#include <hip/hip_runtime.h>
#include <stdint.h>

#define NF 51
#define NFP 52              // NF padded to float4 multiple
#define UNITS 128
#define G3 384
#define OUT_C 102
#define NW 13158            // UNITS*OUT_C + OUT_C
#define GAMMA 28
#define KW_ELEMS 368424     // GAMMA * NW
#define BATCH 8192
#define SEQ_T 64
#define TSTEPS 50           // 64 - LAG(14)
#define NDEC 27
#define BR 32               // batch rows per block
#define THREADS 256
#define RPT 16              // rows per thread (key knob: L1/VALU ratio = 8/RPT)
#define CCONST 0.5413248546129181f  // log(expm1(1.0))

// ---------- JAX threefry2x32 (20 rounds), host+device ----------
__host__ __device__ __forceinline__ void tf2x32(uint32_t k0, uint32_t k1,
    uint32_t x0, uint32_t x1, uint32_t& o0, uint32_t& o1)
{
  uint32_t ks2 = k0 ^ k1 ^ 0x1BD11BDAu;
  x0 += k0; x1 += k1;
#define TF_R(r) { x0 += x1; x1 = (x1 << (r)) | (x1 >> (32 - (r))); x1 ^= x0; }
  TF_R(13) TF_R(15) TF_R(26) TF_R(6)  x0 += k1;  x1 += ks2 + 1u;
  TF_R(17) TF_R(29) TF_R(16) TF_R(24) x0 += ks2; x1 += k0 + 2u;
  TF_R(13) TF_R(15) TF_R(26) TF_R(6)  x0 += k0;  x1 += k1 + 3u;
  TF_R(17) TF_R(29) TF_R(16) TF_R(24) x0 += k1;  x1 += ks2 + 4u;
  TF_R(13) TF_R(15) TF_R(26) TF_R(6)  x0 += ks2; x1 += k0 + 5u;
#undef TF_R
  o0 = x0; o1 = x1;
}

// XLA ErfInv32 (Giles)
__device__ __forceinline__ float erfinv_f(float x) {
  float w = -log1pf(-x * x);
  float p;
  if (w < 5.0f) {
    w -= 2.5f;
    p = 2.81022636e-08f;
    p = fmaf(p, w, 3.43273939e-07f);
    p = fmaf(p, w, -3.5233877e-06f);
    p = fmaf(p, w, -4.39150654e-06f);
    p = fmaf(p, w, 0.00021858087f);
    p = fmaf(p, w, -0.00125372503f);
    p = fmaf(p, w, -0.00417768164f);
    p = fmaf(p, w, 0.246640727f);
    p = fmaf(p, w, 1.50140941f);
  } else {
    w = sqrtf(w) - 3.0f;
    p = -0.000200214257f;
    p = fmaf(p, w, 0.000100950558f);
    p = fmaf(p, w, 0.00134934322f);
    p = fmaf(p, w, -0.00367342844f);
    p = fmaf(p, w, 0.00573950773f);
    p = fmaf(p, w, -0.0076224613f);
    p = fmaf(p, w, 0.00943887047f);
    p = fmaf(p, w, 1.00167406f);
    p = fmaf(p, w, 2.83297682f);
  }
  return p * x;
}

// jax.random.normal element i — partitionable threefry (verified R3):
// bits = y0 ^ y1 of threefry2x32(key, hi32(i)=0, lo32(i)=i)
__device__ __forceinline__ float jax_normal(uint32_t k0, uint32_t k1, uint32_t i)
{
  uint32_t y0, y1;
  tf2x32(k0, k1, 0u, i, y0, y1);
  uint32_t bits = y0 ^ y1;
  uint32_t fb = (bits >> 9) | 0x3f800000u;
  float f = __uint_as_float(fb) - 1.0f;       // [0,1)
  const float lo = -0.99999994f;              // nextafter(-1,0) f32
  const float d  = 1.99999994f;               // 1 - lo
  float u = __fadd_rn(__fmul_rn(f, d), lo);   // XLA uses mul+add (no fma)
  u = fmaxf(lo, u);
  return 1.41421354f * erfinv_f(u);
}

__device__ __forceinline__ float softplus_f(float x) {
  return fmaxf(x, 0.0f) + log1pf(expf(-fabsf(x)));
}
__device__ __forceinline__ float sigmoid_f(float x) {
  return 1.0f / (1.0f + expf(-x));
}

// ---------- prep kernel 1: sample the 28 decoder weight sets ----------
__global__ void sample_w_kernel(const float* __restrict__ post_loc,
                                const float* __restrict__ post_rho,
                                float* __restrict__ wout,
                                uint32_t kw0, uint32_t kw1)
{
  int i = blockIdx.x * 256 + threadIdx.x;
  if (i >= KW_ELEMS) return;
  int widx = i % NW;
  float eps = jax_normal(kw0, kw1, (uint32_t)i);
  float sc = 1e-5f + 0.02f * softplus_f(CCONST + post_rho[widx]);
  wout[i] = fmaf(sc, eps, post_loc[widx]);
}

// ---------- prep kernel 2: pad Wx (51,384) -> WxP (52,384), row 51 = 0 ----------
__global__ void pad_wx_kernel(const float* __restrict__ Wx, float* __restrict__ WxP)
{
  int i = blockIdx.x * 256 + threadIdx.x;
  if (i >= NFP * G3) return;
  WxP[i] = (i < NF * G3) ? Wx[i] : 0.0f;
}

// ---------- main kernel: one block = 32 batch rows, 256 threads ----------
// wave w: ug = w&1 selects unit half (u = lane + 64*ug), rg = w>>1 selects
// 16-row group. Each thread: 1 unit column x 16 rows -> weight bytes/FMA
// = 1/16 -> L1 demand ~50% of VALU issue (was 2x oversubscribed at R=4).
__global__ __launch_bounds__(THREADS, 1) void irnn_main(
    const float* __restrict__ x,     // (8192, 64, 51)
    const float* __restrict__ Wh,    // (128, 384)
    const float* __restrict__ WxP,   // (52, 384) padded
    const float* __restrict__ gbias, // (2, 384)
    const float* __restrict__ Wdec,  // (28, 13158) sampled
    float* __restrict__ out,         // (8192, 28, 102)
    uint32_t ks0, uint32_t ks1)
{
  __shared__ float h_lds[BR][UNITS];   // 16 KB
  __shared__ float s_lds[BR][NFP];     // 6.5 KB (col 51 kept at 0)
  __shared__ float t_lds[BR][OUT_C];   // 12.75 KB

  const int tid  = threadIdx.x;
  const int b0   = blockIdx.x * BR;
  const int lane = tid & 63;
  const int wv   = tid >> 6;          // 0..3
  const int ug   = wv & 1;
  const int rg   = wv >> 1;
  const int u    = lane + 64 * ug;    // unit 0..127
  const int r0   = rg * RPT;          // rows r0..r0+15

  // gate biases for this unit
  const float bz  = gbias[u]           + gbias[G3 + u];
  const float brg = gbias[UNITS + u]   + gbias[G3 + UNITS + u];
  const float bxh = gbias[2*UNITS + u];
  const float brh = gbias[G3 + 2*UNITS + u];

  float hreg[RPT];
  #pragma unroll
  for (int r = 0; r < RPT; ++r) hreg[r] = 0.f;
  for (int i = tid; i < BR * UNITS; i += THREADS) (&h_lds[0][0])[i] = 0.f;
  for (int i = tid; i < BR * NFP;   i += THREADS) (&s_lds[0][0])[i] = 0.f;
  __syncthreads();

  // ---- GRU step: h/s from LDS (wave-broadcast b128), weights scalar-coalesced
  auto gru_update = [&]() {
    float az[RPT] = {}, ar[RPT] = {}, axh[RPT] = {}, arh[RPT] = {};
    #pragma unroll 2
    for (int kk = 0; kk < UNITS; kk += 4) {
      float wz[4], wr[4], wh[4];
      #pragma unroll
      for (int q = 0; q < 4; ++q) {
        const float* row = Wh + (kk + q) * G3;
        wz[q] = row[u]; wr[q] = row[UNITS + u]; wh[q] = row[2*UNITS + u];
      }
      #pragma unroll
      for (int r = 0; r < RPT; ++r) {
        float4 h4 = *(const float4*)&h_lds[r0 + r][kk];
        az[r]  = fmaf(h4.x, wz[0], az[r]);  az[r]  = fmaf(h4.y, wz[1], az[r]);
        az[r]  = fmaf(h4.z, wz[2], az[r]);  az[r]  = fmaf(h4.w, wz[3], az[r]);
        ar[r]  = fmaf(h4.x, wr[0], ar[r]);  ar[r]  = fmaf(h4.y, wr[1], ar[r]);
        ar[r]  = fmaf(h4.z, wr[2], ar[r]);  ar[r]  = fmaf(h4.w, wr[3], ar[r]);
        arh[r] = fmaf(h4.x, wh[0], arh[r]); arh[r] = fmaf(h4.y, wh[1], arh[r]);
        arh[r] = fmaf(h4.z, wh[2], arh[r]); arh[r] = fmaf(h4.w, wh[3], arh[r]);
      }
    }
    #pragma unroll 2
    for (int kk = 0; kk < NFP; kk += 4) {
      float wz[4], wr[4], wh[4];
      #pragma unroll
      for (int q = 0; q < 4; ++q) {
        const float* row = WxP + (kk + q) * G3;
        wz[q] = row[u]; wr[q] = row[UNITS + u]; wh[q] = row[2*UNITS + u];
      }
      #pragma unroll
      for (int r = 0; r < RPT; ++r) {
        float4 s4 = *(const float4*)&s_lds[r0 + r][kk];
        az[r]  = fmaf(s4.x, wz[0], az[r]);  az[r]  = fmaf(s4.y, wz[1], az[r]);
        az[r]  = fmaf(s4.z, wz[2], az[r]);  az[r]  = fmaf(s4.w, wz[3], az[r]);
        ar[r]  = fmaf(s4.x, wr[0], ar[r]);  ar[r]  = fmaf(s4.y, wr[1], ar[r]);
        ar[r]  = fmaf(s4.z, wr[2], ar[r]);  ar[r]  = fmaf(s4.w, wr[3], ar[r]);
        axh[r] = fmaf(s4.x, wh[0], axh[r]); axh[r] = fmaf(s4.y, wh[1], axh[r]);
        axh[r] = fmaf(s4.z, wh[2], axh[r]); axh[r] = fmaf(s4.w, wh[3], axh[r]);
      }
    }
    #pragma unroll
    for (int r = 0; r < RPT; ++r) {
      float z  = sigmoid_f(az[r] + bz);
      float rr = sigmoid_f(ar[r] + brg);
      float hh = tanhf(axh[r] + bxh + rr * (arh[r] + brh));
      hreg[r] = z * hreg[r] + (1.0f - z) * hh;
    }
  };

  auto write_h = [&]() {
    #pragma unroll
    for (int r = 0; r < RPT; ++r) h_lds[r0 + r][u] = hreg[r];
  };

  // ---- sampled head: t = h @ K_g + b_g (raw t -> t_lds, transformed -> out)
  const int tc  = tid & 127;   // col (active < 102)
  const int trg = tid >> 7;    // 0..1 -> 16 rows each
  auto tgemm = [&](int g) {
    if (tc < OUT_C) {
      const float* K = Wdec + (size_t)g * NW;
      float acc[RPT] = {};
      #pragma unroll 2
      for (int kk = 0; kk < UNITS; kk += 4) {
        float kw[4];
        #pragma unroll
        for (int q = 0; q < 4; ++q) kw[q] = K[(kk + q) * OUT_C + tc];
        #pragma unroll
        for (int r = 0; r < RPT; ++r) {
          float4 h4 = *(const float4*)&h_lds[trg * RPT + r][kk];
          acc[r] = fmaf(h4.x, kw[0], acc[r]); acc[r] = fmaf(h4.y, kw[1], acc[r]);
          acc[r] = fmaf(h4.z, kw[2], acc[r]); acc[r] = fmaf(h4.w, kw[3], acc[r]);
        }
      }
      float kb = K[UNITS * OUT_C + tc];
      #pragma unroll
      for (int r = 0; r < RPT; ++r) {
        float tv = acc[r] + kb;
        t_lds[trg * RPT + r][tc] = tv;
        float ov = (tc < NF) ? tv
                             : (1e-5f + 0.05f * softplus_f(CCONST + tv));
        out[(size_t)(b0 + trg * RPT + r) * (GAMMA * OUT_C) + g * OUT_C + tc] = ov;
      }
    }
  };

  // ---- decoder input: s = loc + scale * eps_s[j], eps_s shape (27,8192,51)
  auto sphase = [&](int j) {
    for (int idx = tid; idx < BR * NF; idx += THREADS) {
      int r = idx / NF, f = idx - r * NF;
      float loc = t_lds[r][f];
      float sc = 1e-5f + 0.05f * softplus_f(CCONST + t_lds[r][NF + f]);
      uint32_t gi = (uint32_t)((j * BATCH + b0 + r) * NF + f);
      float es = jax_normal(ks0, ks1, gi);
      s_lds[r][f] = fmaf(sc, es, loc);
    }
  };

  // ---- encoder: 50 steps ----
  for (int t = 0; t < TSTEPS; ++t) {
    for (int idx = tid; idx < BR * NF; idx += THREADS) {
      int r = idx / NF, f = idx - r * NF;
      s_lds[r][f] = x[(size_t)(b0 + r) * (SEQ_T * NF) + t * NF + f];
    }
    __syncthreads();
    gru_update();
    __syncthreads();
    write_h();
  }
  __syncthreads();
  tgemm(0);
  __syncthreads();

  // ---- decoder: 27 steps ----
  for (int j = 0; j < NDEC; ++j) {
    sphase(j);
    __syncthreads();
    gru_update();
    __syncthreads();
    write_h();
    __syncthreads();
    tgemm(j + 1);
    __syncthreads();
  }
}

extern "C" void kernel_launch(void* const* d_in, const int* in_sizes, int n_in,
                              void* d_out, int out_size, void* d_ws, size_t ws_size,
                              hipStream_t stream)
{
  const float* x    = (const float*)d_in[0];
  const float* gk   = (const float*)d_in[1];
  const float* grk  = (const float*)d_in[2];
  const float* gb   = (const float*)d_in[3];
  const float* ploc = (const float*)d_in[4];
  const float* prho = (const float*)d_in[5];

  float* wdec = (float*)d_ws;                  // 368424 floats (1.47 MB)
  float* wxp  = wdec + KW_ELEMS;               // 52*384 floats (80 KB)

  // keys: fold_in(key(42), d) = threefry2x32(key=[0,42], counts=[0,d])
  uint32_t kw0, kw1, ksd0, ksd1;
  tf2x32(0u, 42u, 0u, 0u, kw0, kw1);
  tf2x32(0u, 42u, 0u, 1u, ksd0, ksd1);

  sample_w_kernel<<<(KW_ELEMS + 255) / 256, 256, 0, stream>>>(ploc, prho, wdec, kw0, kw1);
  pad_wx_kernel<<<(NFP * G3 + 255) / 256, 256, 0, stream>>>(gk, wxp);
  irnn_main<<<BATCH / BR, THREADS, 0, stream>>>(x, grk, wxp, gb, wdec,
                                                (float*)d_out, ksd0, ksd1);
}

// Round 5
// 2335.392 us; speedup vs baseline: 1.5475x; 1.5475x over previous
//
#include <hip/hip_runtime.h>
#include <stdint.h>

#define NF 51
#define NFP 52              // NF padded to float4 multiple
#define UNITS 128
#define G3 384
#define OUT_C 102
#define NW 13158            // UNITS*OUT_C + OUT_C
#define GAMMA 28
#define KW_ELEMS 368424     // GAMMA * NW
#define BATCH 8192
#define SEQ_T 64
#define TSTEPS 50           // 64 - LAG(14)
#define NDEC 27
#define BR 32               // batch rows per block
#define THREADS 1024        // 16 waves = 4/SIMD: TLP hides weight-load latency
#define CCONST 0.5413248546129181f  // log(expm1(1.0))

// ---------- JAX threefry2x32 (20 rounds), host+device ----------
__host__ __device__ __forceinline__ void tf2x32(uint32_t k0, uint32_t k1,
    uint32_t x0, uint32_t x1, uint32_t& o0, uint32_t& o1)
{
  uint32_t ks2 = k0 ^ k1 ^ 0x1BD11BDAu;
  x0 += k0; x1 += k1;
#define TF_R(r) { x0 += x1; x1 = (x1 << (r)) | (x1 >> (32 - (r))); x1 ^= x0; }
  TF_R(13) TF_R(15) TF_R(26) TF_R(6)  x0 += k1;  x1 += ks2 + 1u;
  TF_R(17) TF_R(29) TF_R(16) TF_R(24) x0 += ks2; x1 += k0 + 2u;
  TF_R(13) TF_R(15) TF_R(26) TF_R(6)  x0 += k0;  x1 += k1 + 3u;
  TF_R(17) TF_R(29) TF_R(16) TF_R(24) x0 += k1;  x1 += ks2 + 4u;
  TF_R(13) TF_R(15) TF_R(26) TF_R(6)  x0 += ks2; x1 += k0 + 5u;
#undef TF_R
  o0 = x0; o1 = x1;
}

// XLA ErfInv32 (Giles)
__device__ __forceinline__ float erfinv_f(float x) {
  float w = -log1pf(-x * x);
  float p;
  if (w < 5.0f) {
    w -= 2.5f;
    p = 2.81022636e-08f;
    p = fmaf(p, w, 3.43273939e-07f);
    p = fmaf(p, w, -3.5233877e-06f);
    p = fmaf(p, w, -4.39150654e-06f);
    p = fmaf(p, w, 0.00021858087f);
    p = fmaf(p, w, -0.00125372503f);
    p = fmaf(p, w, -0.00417768164f);
    p = fmaf(p, w, 0.246640727f);
    p = fmaf(p, w, 1.50140941f);
  } else {
    w = sqrtf(w) - 3.0f;
    p = -0.000200214257f;
    p = fmaf(p, w, 0.000100950558f);
    p = fmaf(p, w, 0.00134934322f);
    p = fmaf(p, w, -0.00367342844f);
    p = fmaf(p, w, 0.00573950773f);
    p = fmaf(p, w, -0.0076224613f);
    p = fmaf(p, w, 0.00943887047f);
    p = fmaf(p, w, 1.00167406f);
    p = fmaf(p, w, 2.83297682f);
  }
  return p * x;
}

// jax.random.normal element i — partitionable threefry (verified R3):
// bits = y0 ^ y1 of threefry2x32(key, hi32(i)=0, lo32(i)=i)
__device__ __forceinline__ float jax_normal(uint32_t k0, uint32_t k1, uint32_t i)
{
  uint32_t y0, y1;
  tf2x32(k0, k1, 0u, i, y0, y1);
  uint32_t bits = y0 ^ y1;
  uint32_t fb = (bits >> 9) | 0x3f800000u;
  float f = __uint_as_float(fb) - 1.0f;       // [0,1)
  const float lo = -0.99999994f;              // nextafter(-1,0) f32
  const float d  = 1.99999994f;               // 1 - lo
  float u = __fadd_rn(__fmul_rn(f, d), lo);   // XLA uses mul+add (no fma)
  u = fmaxf(lo, u);
  return 1.41421354f * erfinv_f(u);
}

__device__ __forceinline__ float softplus_f(float x) {
  return fmaxf(x, 0.0f) + log1pf(expf(-fabsf(x)));
}
__device__ __forceinline__ float sigmoid_f(float x) {
  return 1.0f / (1.0f + expf(-x));
}

// ---------- prep kernel 1: sample the 28 decoder weight sets ----------
__global__ void sample_w_kernel(const float* __restrict__ post_loc,
                                const float* __restrict__ post_rho,
                                float* __restrict__ wout,
                                uint32_t kw0, uint32_t kw1)
{
  int i = blockIdx.x * 256 + threadIdx.x;
  if (i >= KW_ELEMS) return;
  int widx = i % NW;
  float eps = jax_normal(kw0, kw1, (uint32_t)i);
  float sc = 1e-5f + 0.02f * softplus_f(CCONST + post_rho[widx]);
  wout[i] = fmaf(sc, eps, post_loc[widx]);
}

// ---------- prep kernel 2: pad Wx (51,384) -> WxP (52,384), row 51 = 0 ----------
__global__ void pad_wx_kernel(const float* __restrict__ Wx, float* __restrict__ WxP)
{
  int i = blockIdx.x * 256 + threadIdx.x;
  if (i >= NFP * G3) return;
  WxP[i] = (i < NF * G3) ? Wx[i] : 0.0f;
}

// ---------- main kernel: 32 batch rows/block, 1024 threads (16 waves) ----------
// wave wv: ug = wv&1 -> unit half (u = lane + 64*ug), rg = wv>>1 -> 4-row group.
// Thread = 1 unit x 4 rows: per 4-k chunk = 12 coalesced weight loads +
// 4 broadcast ds_read_b128 + 48 FMAs. Latency hidden by 4 waves/SIMD.
__global__ __launch_bounds__(THREADS, 4) void irnn_main(
    const float* __restrict__ x,     // (8192, 64, 51)
    const float* __restrict__ Wh,    // (128, 384)
    const float* __restrict__ WxP,   // (52, 384) padded
    const float* __restrict__ gbias, // (2, 384)
    const float* __restrict__ Wdec,  // (28, 13158) sampled
    float* __restrict__ out,         // (8192, 28, 102)
    uint32_t ks0, uint32_t ks1)
{
  __shared__ float h_lds[BR][UNITS];   // 16 KB
  __shared__ float s_lds[BR][NFP];     // 6.5 KB (col 51 kept at 0)
  __shared__ float t_lds[BR][OUT_C];   // 12.75 KB

  const int tid  = threadIdx.x;
  const int b0   = blockIdx.x * BR;
  const int lane = tid & 63;
  const int wv   = tid >> 6;          // 0..15
  const int ug   = wv & 1;
  const int rg   = wv >> 1;           // 0..7
  const int u    = lane + 64 * ug;    // unit 0..127
  const int r0   = rg * 4;            // rows r0..r0+3

  // gate biases for this unit
  const float bz  = gbias[u]           + gbias[G3 + u];
  const float brg = gbias[UNITS + u]   + gbias[G3 + UNITS + u];
  const float bxh = gbias[2*UNITS + u];
  const float brh = gbias[G3 + 2*UNITS + u];

  float hreg[4] = {0.f, 0.f, 0.f, 0.f};
  for (int i = tid; i < BR * UNITS; i += THREADS) (&h_lds[0][0])[i] = 0.f;
  for (int i = tid; i < BR * NFP;   i += THREADS) (&s_lds[0][0])[i] = 0.f;
  __syncthreads();

  // ---- GRU step: h/s via broadcast b128 from LDS, weights coalesced global
  auto gru_update = [&]() {
    float az[4] = {}, ar[4] = {}, axh[4] = {}, arh[4] = {};
    #pragma unroll 2
    for (int kk = 0; kk < UNITS; kk += 4) {
      float wz[4], wr[4], wh[4];
      #pragma unroll
      for (int q = 0; q < 4; ++q) {
        const float* row = Wh + (kk + q) * G3;
        wz[q] = row[u]; wr[q] = row[UNITS + u]; wh[q] = row[2*UNITS + u];
      }
      #pragma unroll
      for (int r = 0; r < 4; ++r) {
        float4 h4 = *(const float4*)&h_lds[r0 + r][kk];
        az[r]  = fmaf(h4.x, wz[0], az[r]);  az[r]  = fmaf(h4.y, wz[1], az[r]);
        az[r]  = fmaf(h4.z, wz[2], az[r]);  az[r]  = fmaf(h4.w, wz[3], az[r]);
        ar[r]  = fmaf(h4.x, wr[0], ar[r]);  ar[r]  = fmaf(h4.y, wr[1], ar[r]);
        ar[r]  = fmaf(h4.z, wr[2], ar[r]);  ar[r]  = fmaf(h4.w, wr[3], ar[r]);
        arh[r] = fmaf(h4.x, wh[0], arh[r]); arh[r] = fmaf(h4.y, wh[1], arh[r]);
        arh[r] = fmaf(h4.z, wh[2], arh[r]); arh[r] = fmaf(h4.w, wh[3], arh[r]);
      }
    }
    #pragma unroll 2
    for (int kk = 0; kk < NFP; kk += 4) {
      float wz[4], wr[4], wh[4];
      #pragma unroll
      for (int q = 0; q < 4; ++q) {
        const float* row = WxP + (kk + q) * G3;
        wz[q] = row[u]; wr[q] = row[UNITS + u]; wh[q] = row[2*UNITS + u];
      }
      #pragma unroll
      for (int r = 0; r < 4; ++r) {
        float4 s4 = *(const float4*)&s_lds[r0 + r][kk];
        az[r]  = fmaf(s4.x, wz[0], az[r]);  az[r]  = fmaf(s4.y, wz[1], az[r]);
        az[r]  = fmaf(s4.z, wz[2], az[r]);  az[r]  = fmaf(s4.w, wz[3], az[r]);
        ar[r]  = fmaf(s4.x, wr[0], ar[r]);  ar[r]  = fmaf(s4.y, wr[1], ar[r]);
        ar[r]  = fmaf(s4.z, wr[2], ar[r]);  ar[r]  = fmaf(s4.w, wr[3], ar[r]);
        axh[r] = fmaf(s4.x, wh[0], axh[r]); axh[r] = fmaf(s4.y, wh[1], axh[r]);
        axh[r] = fmaf(s4.z, wh[2], axh[r]); axh[r] = fmaf(s4.w, wh[3], axh[r]);
      }
    }
    #pragma unroll
    for (int r = 0; r < 4; ++r) {
      float z  = sigmoid_f(az[r] + bz);
      float rr = sigmoid_f(ar[r] + brg);
      float hh = tanhf(axh[r] + bxh + rr * (arh[r] + brh));
      hreg[r] = z * hreg[r] + (1.0f - z) * hh;
    }
  };

  auto write_h = [&]() {
    #pragma unroll
    for (int r = 0; r < 4; ++r) h_lds[r0 + r][u] = hreg[r];
  };

  // ---- sampled head: t = h @ K_g + b_g (raw t -> t_lds, transformed -> out)
  const int tc  = tid & 127;   // col (active < 102)
  const int trg = tid >> 7;    // 0..7 -> 4 rows each
  auto tgemm = [&](int g) {
    if (tc < OUT_C) {
      const float* K = Wdec + (size_t)g * NW;
      float acc[4] = {};
      #pragma unroll 2
      for (int kk = 0; kk < UNITS; kk += 4) {
        float kw[4];
        #pragma unroll
        for (int q = 0; q < 4; ++q) kw[q] = K[(kk + q) * OUT_C + tc];
        #pragma unroll
        for (int r = 0; r < 4; ++r) {
          float4 h4 = *(const float4*)&h_lds[trg * 4 + r][kk];
          acc[r] = fmaf(h4.x, kw[0], acc[r]); acc[r] = fmaf(h4.y, kw[1], acc[r]);
          acc[r] = fmaf(h4.z, kw[2], acc[r]); acc[r] = fmaf(h4.w, kw[3], acc[r]);
        }
      }
      float kb = K[UNITS * OUT_C + tc];
      #pragma unroll
      for (int r = 0; r < 4; ++r) {
        float tv = acc[r] + kb;
        t_lds[trg * 4 + r][tc] = tv;
        float ov = (tc < NF) ? tv
                             : (1e-5f + 0.05f * softplus_f(CCONST + tv));
        out[(size_t)(b0 + trg * 4 + r) * (GAMMA * OUT_C) + g * OUT_C + tc] = ov;
      }
    }
  };

  // ---- decoder input: s = loc + scale * eps_s[j], eps_s shape (27,8192,51)
  auto sphase = [&](int j) {
    for (int idx = tid; idx < BR * NF; idx += THREADS) {
      int r = idx / NF, f = idx - r * NF;
      float loc = t_lds[r][f];
      float sc = 1e-5f + 0.05f * softplus_f(CCONST + t_lds[r][NF + f]);
      uint32_t gi = (uint32_t)((j * BATCH + b0 + r) * NF + f);
      float es = jax_normal(ks0, ks1, gi);
      s_lds[r][f] = fmaf(sc, es, loc);
    }
  };

  // ---- encoder: 50 steps ----
  for (int t = 0; t < TSTEPS; ++t) {
    for (int idx = tid; idx < BR * NF; idx += THREADS) {
      int r = idx / NF, f = idx - r * NF;
      s_lds[r][f] = x[(size_t)(b0 + r) * (SEQ_T * NF) + t * NF + f];
    }
    __syncthreads();
    gru_update();
    __syncthreads();
    write_h();
  }
  __syncthreads();
  tgemm(0);
  __syncthreads();

  // ---- decoder: 27 steps ----
  for (int j = 0; j < NDEC; ++j) {
    sphase(j);
    __syncthreads();
    gru_update();
    __syncthreads();
    write_h();
    __syncthreads();
    tgemm(j + 1);
    __syncthreads();
  }
}

extern "C" void kernel_launch(void* const* d_in, const int* in_sizes, int n_in,
                              void* d_out, int out_size, void* d_ws, size_t ws_size,
                              hipStream_t stream)
{
  const float* x    = (const float*)d_in[0];
  const float* gk   = (const float*)d_in[1];
  const float* grk  = (const float*)d_in[2];
  const float* gb   = (const float*)d_in[3];
  const float* ploc = (const float*)d_in[4];
  const float* prho = (const float*)d_in[5];

  float* wdec = (float*)d_ws;                  // 368424 floats (1.47 MB)
  float* wxp  = wdec + KW_ELEMS;               // 52*384 floats (80 KB)

  // keys: fold_in(key(42), d) = threefry2x32(key=[0,42], counts=[0,d])
  uint32_t kw0, kw1, ksd0, ksd1;
  tf2x32(0u, 42u, 0u, 0u, kw0, kw1);
  tf2x32(0u, 42u, 0u, 1u, ksd0, ksd1);

  sample_w_kernel<<<(KW_ELEMS + 255) / 256, 256, 0, stream>>>(ploc, prho, wdec, kw0, kw1);
  pad_wx_kernel<<<(NFP * G3 + 255) / 256, 256, 0, stream>>>(gk, wxp);
  irnn_main<<<BATCH / BR, THREADS, 0, stream>>>(x, grk, wxp, gb, wdec,
                                                (float*)d_out, ksd0, ksd1);
}